// Round 8
// baseline (480.678 us; speedup 1.0000x reference)
//
#include <hip/hip_runtime.h>

typedef unsigned short u16;
typedef unsigned int u32;
typedef __attribute__((ext_vector_type(8))) short bf16x8;
typedef __attribute__((ext_vector_type(4))) float f32x4;

#define LDSN 13312      // nodes per LDS range (26 KB of packed u16 counters)
#define CHUNK 131072    // edges per chunk (2^17) -> ~2.6 slots/node/chunk, dense fill lines

__device__ __forceinline__ float bf_lo(u32 u){ return __uint_as_float(u << 16); }
__device__ __forceinline__ float bf_hi(u32 u){ return __uint_as_float(u & 0xffff0000u); }
__device__ __forceinline__ float bf2f(u16 v){ return __uint_as_float((u32)v << 16); }
__device__ __forceinline__ u16 f2bf(float f){
    u32 u = __float_as_uint(f);
    u32 r = (u + 0x7fffu + ((u >> 16) & 1u)) >> 16;
    return (u16)r;
}
__device__ __forceinline__ u32 pack2(float a, float b){
    return (u32)f2bf(a) | ((u32)f2bf(b) << 16);
}

// ======== fusedA: packed-LDS hist+rank || weight swizzle || ntgemm_M || ntgemm_H ========
__global__ __launch_bounds__(256) void fusedA_kernel(
    const int* __restrict__ d0, const int* __restrict__ d1, const int* __restrict__ d2,
    u16* __restrict__ rk0, u16* __restrict__ rk1, u16* __restrict__ rk2,
    int E0, int E1, int E2, int n0, int n1, int n2,
    int c0, int c1, int c2, int R0, int R1, int R2,
    u16* __restrict__ C0, u16* __restrict__ C1, u16* __restrict__ C2, int HB2,
    const float* __restrict__ Wf0, const float* __restrict__ Wf1,
    const float* __restrict__ Wf2, const float* __restrict__ Wf3,
    const float* __restrict__ Wf4, const float* __restrict__ Wf5,
    u16* __restrict__ WF,
    const float* __restrict__ Xm, const float* __restrict__ Wm,
    const float* __restrict__ bm, u16* __restrict__ Tm, int NM,
    const float* __restrict__ Xh, const float* __restrict__ Wh,
    const float* __restrict__ bh, u16* __restrict__ Th, int NH,
    int gm, int gh)
{
    __shared__ u32 lc[LDSN / 2];
    int bid = blockIdx.x;
    if (bid < HB2){
        const int* dp; u16 *rk, *cp; int E, n, cc, rr;
        if (bid < c0 * R0){ dp = d0; rk = rk0; cp = C0; E = E0; n = n0; cc = bid / R0; rr = bid % R0; }
        else if (bid < c0 * R0 + c1 * R1){ int l = bid - c0 * R0; dp = d1; rk = rk1; cp = C1; E = E1; n = n1; cc = l / R1; rr = l % R1; }
        else { int l = bid - c0 * R0 - c1 * R1; dp = d2; rk = rk2; cp = C2; E = E2; n = n2; cc = l / R2; rr = l % R2; }
        for (int i = threadIdx.x; i < LDSN / 2; i += 256) lc[i] = 0;
        __syncthreads();
        int r0 = rr * LDSN, r1 = min(r0 + LDSN, n);
        int i0 = cc * CHUNK, i1 = min(i0 + CHUNK, E);
        int i = i0 + threadIdx.x;
        // 4-way ILP over independent edges
        for (; i + 768 < i1; i += 1024){
            int xa = dp[i], xb = dp[i + 256], xc = dp[i + 512], xd = dp[i + 768];
            if ((unsigned)xa < (unsigned)n && xa >= r0 && xa < r1){
                int lx = xa - r0; int sh = (lx & 1) << 4;
                u32 old = atomicAdd(&lc[lx >> 1], 1u << sh);
                rk[i] = (u16)((old >> sh) & 0xffffu);
            }
            if ((unsigned)xb < (unsigned)n && xb >= r0 && xb < r1){
                int lx = xb - r0; int sh = (lx & 1) << 4;
                u32 old = atomicAdd(&lc[lx >> 1], 1u << sh);
                rk[i + 256] = (u16)((old >> sh) & 0xffffu);
            }
            if ((unsigned)xc < (unsigned)n && xc >= r0 && xc < r1){
                int lx = xc - r0; int sh = (lx & 1) << 4;
                u32 old = atomicAdd(&lc[lx >> 1], 1u << sh);
                rk[i + 512] = (u16)((old >> sh) & 0xffffu);
            }
            if ((unsigned)xd < (unsigned)n && xd >= r0 && xd < r1){
                int lx = xd - r0; int sh = (lx & 1) << 4;
                u32 old = atomicAdd(&lc[lx >> 1], 1u << sh);
                rk[i + 768] = (u16)((old >> sh) & 0xffffu);
            }
        }
        for (; i < i1; i += 256){
            int x = dp[i];
            if ((unsigned)x < (unsigned)n && x >= r0 && x < r1){
                int lx = x - r0;
                int sh = (lx & 1) << 4;
                u32 old = atomicAdd(&lc[lx >> 1], 1u << sh);
                rk[i] = (u16)((old >> sh) & 0xffffu);
            }
        }
        __syncthreads();
        u16* op = cp + (size_t)cc * n;
        for (int x = r0 + threadIdx.x; x < r1; x += 256){
            int lx = x - r0;
            op[x] = (u16)((lc[lx >> 1] >> ((lx & 1) << 4)) & 0xffffu);
        }
        return;
    }
    bid -= HB2;
    if (bid < 6){
        const float* W = bid == 0 ? Wf0 : bid == 1 ? Wf1 : bid == 2 ? Wf2 :
                         bid == 3 ? Wf3 : bid == 4 ? Wf4 : Wf5;
        u16* dst = WF + (size_t)bid * 16384;
        #pragma unroll 4
        for (int k = 0; k < 64; ++k){
            int i = k * 256 + threadIdx.x;
            int j   = i & 7;
            int l16 = (i >> 3) & 15;
            int qd  = (i >> 7) & 3;
            int q   = (i >> 9) & 3;
            int tt  = (i >> 11) & 1;
            int w   = (i >> 12) & 3;
            dst[i] = f2bf(W[(q * 32 + qd * 8 + j) * 128 + (w * 32 + tt * 16 + l16)]);
        }
        return;
    }
    bid -= 6;
    const float *A, *W, *bias; u16* C; int N, lgrid, lbid;
    if (bid < gm){ A = Xm; W = Wm; bias = bm; C = Tm; N = NM; lgrid = gm; lbid = bid; }
    else         { A = Xh; W = Wh; bias = bh; C = Th; N = NH; lgrid = gh; lbid = bid - gm; }

    int tid = threadIdx.x;
    int wave = tid >> 6, lane = tid & 63;
    int colHalf = wave & 1;
    int ln16 = lane & 15, quad = lane >> 4;

    bf16x8 Bfrag[4][4];
    #pragma unroll
    for (int t = 0; t < 4; ++t){
        int col = colHalf * 64 + t * 16 + ln16;
        #pragma unroll
        for (int q = 0; q < 4; ++q){
            bf16x8 f;
            #pragma unroll
            for (int j = 0; j < 8; ++j)
                f[j] = (short)f2bf(W[(q * 32 + quad * 8 + j) * 128 + col]);
            Bfrag[t][q] = f;
        }
    }
    float bv[4];
    #pragma unroll
    for (int t = 0; t < 4; ++t)
        bv[t] = bias[colHalf * 64 + t * 16 + ln16];

    int rowBlocks = (N + 15) >> 4;
    for (int rb = lbid * 2 + (wave >> 1); rb < rowBlocks; rb += lgrid * 2){
        int row0 = rb * 16;
        int ar = row0 + ln16; if (ar > N - 1) ar = N - 1;
        const float* Arow = A + (size_t)ar * 128 + quad * 8;
        bf16x8 Af[4];
        #pragma unroll
        for (int q = 0; q < 4; ++q){
            f32x4 lo = *(const f32x4*)(Arow + q * 32);
            f32x4 hi = *(const f32x4*)(Arow + q * 32 + 4);
            bf16x8 f;
            #pragma unroll
            for (int j = 0; j < 4; ++j){ f[j] = (short)f2bf(lo[j]); f[4+j] = (short)f2bf(hi[j]); }
            Af[q] = f;
        }
        f32x4 acc[4];
        #pragma unroll
        for (int t = 0; t < 4; ++t) acc[t] = (f32x4){bv[t], bv[t], bv[t], bv[t]};
        #pragma unroll
        for (int q = 0; q < 4; ++q)
            #pragma unroll
            for (int t = 0; t < 4; ++t)
                acc[t] = __builtin_amdgcn_mfma_f32_16x16x32_bf16(Af[q], Bfrag[t][q], acc[t], 0, 0, 0);
        #pragma unroll
        for (int t = 0; t < 4; ++t){
            int col = colHalf * 64 + t * 16 + ln16;
            #pragma unroll
            for (int r = 0; r < 4; ++r){
                int row = row0 + quad * 4 + r;
                if (row < N) C[(size_t)row * 128 + col] = f2bf(acc[t][r]);
            }
        }
    }
}

// ---------------- scan: totals from per-chunk u16 counts (intra-block prefix + partials) ----------------
__global__ __launch_bounds__(256) void scan_blocks_kernel(
    const u16* __restrict__ C0, const u16* __restrict__ C1, const u16* __restrict__ C2,
    int c0, int c1, int c2, int NM, int NH, int n,
    int* __restrict__ off, int* __restrict__ part)
{
    __shared__ int lds[256];
    int tid = threadIdx.x;
    int base = blockIdx.x * 2048 + tid * 8;
    int v[8]; int s = 0;
    #pragma unroll
    for (int j = 0; j < 8; ++j){
        int idx = base + j;
        int tot = 0;
        if (idx < n){
            const u16* cp; int ch, w, x;
            if (idx < NM){ cp = C0; ch = c0; w = NM; x = idx; }
            else if (idx < 2 * NM){ cp = C1; ch = c1; w = NM; x = idx - NM; }
            else { cp = C2; ch = c2; w = NH; x = idx - 2 * NM; }
            for (int cc = 0; cc < ch; ++cc) tot += cp[(size_t)cc * w + x];
        }
        v[j] = s; s += tot;
    }
    lds[tid] = s;
    __syncthreads();
    for (int d = 1; d < 256; d <<= 1){
        int t = (tid >= d) ? lds[tid - d] : 0;
        __syncthreads();
        lds[tid] += t;
        __syncthreads();
    }
    int thrBase = (tid > 0) ? lds[tid - 1] : 0;
    if (tid == 255) part[blockIdx.x] = lds[255];
    #pragma unroll
    for (int j = 0; j < 8; ++j){
        int idx = base + j;
        if (idx < n) off[idx] = thrBase + v[j];
    }
}

// ---------------- colbase: in-thread part prefix; off += prefix; BASE_t[c][x]; off[n] ----------------
__global__ __launch_bounds__(256) void colbase_kernel(
    const u16* __restrict__ C0, const u16* __restrict__ C1, const u16* __restrict__ C2,
    int* __restrict__ B0, int* __restrict__ B1, int* __restrict__ B2,
    int c0, int c1, int c2, int NM, int NH, int n,
    int* __restrict__ off, const int* __restrict__ part)
{
    int idx = blockIdx.x * 256 + threadIdx.x;
    if (idx >= n) return;
    int pb = idx >> 11;
    int p = 0;
    for (int k = 0; k < pb; ++k) p += part[k];
    int run = off[idx] + p;
    off[idx] = run;
    const u16* cp; int* bp; int ch, w, x;
    if (idx < NM){ cp = C0; bp = B0; ch = c0; w = NM; x = idx; }
    else if (idx < 2 * NM){ cp = C1; bp = B1; ch = c1; w = NM; x = idx - NM; }
    else { cp = C2; bp = B2; ch = c2; w = NH; x = idx - 2 * NM; }
    for (int cc = 0; cc < ch; ++cc){
        bp[(size_t)cc * w + x] = run;
        run += cp[(size_t)cc * w + x];
    }
    if (idx == n - 1) off[n] = run;
}

// ===== fill: atomic-free, LDS-free scatter: slot = BASE[chunk][dst] + rank =====
__global__ __launch_bounds__(256) void fill3_kernel(
    const int* __restrict__ s0, const int* __restrict__ s1, const int* __restrict__ s2,
    const int* __restrict__ d0, const int* __restrict__ d1, const int* __restrict__ d2,
    const u16* __restrict__ rk0, const u16* __restrict__ rk1, const u16* __restrict__ rk2,
    int E0, int E1, int E2, int n0, int n1, int n2,
    const int* __restrict__ B0, const int* __restrict__ B1, const int* __restrict__ B2,
    int* __restrict__ slot)
{
    int t = blockIdx.y;
    const int* sp = t == 0 ? s0 : (t == 1 ? s1 : s2);
    const int* dp = t == 0 ? d0 : (t == 1 ? d1 : d2);
    const u16* rk = t == 0 ? rk0 : (t == 1 ? rk1 : rk2);
    const int* bp = t == 0 ? B0 : (t == 1 ? B1 : B2);
    int E = t == 0 ? E0 : (t == 1 ? E1 : E2);
    int n = t == 0 ? n0 : (t == 1 ? n1 : n2);
    int base = blockIdx.x * 1024 + threadIdx.x;
    #pragma unroll
    for (int k = 0; k < 4; ++k){
        int i = base + k * 256;
        if (i < E){
            int x = dp[i];
            if ((unsigned)x < (unsigned)n){
                int cc = i / CHUNK;
                slot[bp[(size_t)cc * n + x] + (int)rk[i]] = sp[i];
            }
        }
    }
}

// ===== gather: 4 rows per wave (prefetched off/slot) — at random-fetch ceiling, unchanged =====
__global__ __launch_bounds__(256) void gather3_kernel(
    const u16* __restrict__ TM, const u16* __restrict__ TH,
    const int* __restrict__ off, const int* __restrict__ slot,
    u32* __restrict__ AGGM, u32* __restrict__ AGGH, int NM, int NH)
{
    int n3 = 2 * NM + NH;
    int wid = (int)((blockIdx.x * 256u + threadIdx.x) >> 6);
    int lane = threadIdx.x & 63;
    int nw = (gridDim.x * 256) >> 6;

    for (int id0 = wid * 4; id0 < n3; id0 += nw * 4){
        int bb[4], dg[4], tk[4], ms[4], ns[4];
        const u16* Ts[4];
        #pragma unroll
        for (int r = 0; r < 4; ++r){
            int id = id0 + r;
            int b = 0, e = 0;
            if (id < n3){ b = off[id]; e = off[id + 1]; }
            bb[r] = b;
            int deg = e - b; dg[r] = deg;
            int take = deg < 64 ? deg : 64; tk[r] = take;
            const u16* Tsrc; int nsrc;
            if (id < NM){ Tsrc = TM; nsrc = NM; }
            else if (id < 2 * NM){ Tsrc = TH; nsrc = NH; }
            else { Tsrc = TM; nsrc = NM; }
            Ts[r] = Tsrc; ns[r] = nsrc;
            int s = 0;
            if (lane < take){
                s = slot[b + lane];
                if ((unsigned)s >= (unsigned)nsrc) s = 0;
            }
            ms[r] = s;
        }

        #pragma unroll
        for (int r = 0; r < 4; ++r){
            int id = id0 + r;
            if (id >= n3) break;
            const u16* Tsrc = Ts[r];
            int take = tk[r];
            float a0=0.f,a1=0.f,b0f=0.f,b1f=0.f,c0=0.f,c1=0.f,d0f=0.f,d1f=0.f;
            float e0=0.f,e1=0.f,f0=0.f,f1=0.f,g0=0.f,g1=0.f,h0=0.f,h1=0.f;
            int j = 0;
            for (; j + 8 <= take; j += 8){
                int i0 = __shfl(ms[r], j);     int i1 = __shfl(ms[r], j + 1);
                int i2 = __shfl(ms[r], j + 2); int i3 = __shfl(ms[r], j + 3);
                int i4 = __shfl(ms[r], j + 4); int i5 = __shfl(ms[r], j + 5);
                int i6 = __shfl(ms[r], j + 6); int i7 = __shfl(ms[r], j + 7);
                u32 u0 = *(const u32*)(Tsrc + (size_t)i0 * 128 + lane * 2);
                u32 u1 = *(const u32*)(Tsrc + (size_t)i1 * 128 + lane * 2);
                u32 u2 = *(const u32*)(Tsrc + (size_t)i2 * 128 + lane * 2);
                u32 u3 = *(const u32*)(Tsrc + (size_t)i3 * 128 + lane * 2);
                u32 u4 = *(const u32*)(Tsrc + (size_t)i4 * 128 + lane * 2);
                u32 u5 = *(const u32*)(Tsrc + (size_t)i5 * 128 + lane * 2);
                u32 u6 = *(const u32*)(Tsrc + (size_t)i6 * 128 + lane * 2);
                u32 u7 = *(const u32*)(Tsrc + (size_t)i7 * 128 + lane * 2);
                a0 += bf_lo(u0); a1 += bf_hi(u0);
                b0f += bf_lo(u1); b1f += bf_hi(u1);
                c0 += bf_lo(u2); c1 += bf_hi(u2);
                d0f += bf_lo(u3); d1f += bf_hi(u3);
                e0 += bf_lo(u4); e1 += bf_hi(u4);
                f0 += bf_lo(u5); f1 += bf_hi(u5);
                g0 += bf_lo(u6); g1 += bf_hi(u6);
                h0 += bf_lo(u7); h1 += bf_hi(u7);
            }
            for (; j + 4 <= take; j += 4){
                int i0 = __shfl(ms[r], j);     int i1 = __shfl(ms[r], j + 1);
                int i2 = __shfl(ms[r], j + 2); int i3 = __shfl(ms[r], j + 3);
                u32 u0 = *(const u32*)(Tsrc + (size_t)i0 * 128 + lane * 2);
                u32 u1 = *(const u32*)(Tsrc + (size_t)i1 * 128 + lane * 2);
                u32 u2 = *(const u32*)(Tsrc + (size_t)i2 * 128 + lane * 2);
                u32 u3 = *(const u32*)(Tsrc + (size_t)i3 * 128 + lane * 2);
                a0 += bf_lo(u0); a1 += bf_hi(u0);
                b0f += bf_lo(u1); b1f += bf_hi(u1);
                c0 += bf_lo(u2); c1 += bf_hi(u2);
                d0f += bf_lo(u3); d1f += bf_hi(u3);
            }
            for (; j < take; ++j){
                int i0 = __shfl(ms[r], j);
                u32 u0 = *(const u32*)(Tsrc + (size_t)i0 * 128 + lane * 2);
                a0 += bf_lo(u0); a1 += bf_hi(u0);
            }
            for (int j2 = bb[r] + 64; j2 < bb[r] + dg[r]; ++j2){
                int i0 = slot[j2];
                if ((unsigned)i0 >= (unsigned)ns[r]) i0 = 0;
                u32 u0 = *(const u32*)(Tsrc + (size_t)i0 * 128 + lane * 2);
                a0 += bf_lo(u0); a1 += bf_hi(u0);
            }
            float s0 = ((a0 + b0f) + (c0 + d0f)) + ((e0 + f0) + (g0 + h0));
            float s1 = ((a1 + b1f) + (c1 + d1f)) + ((e1 + f1) + (g1 + h1));
            float inv = 1.0f / (float)(dg[r] < 1 ? 1 : dg[r]);
            u32 pv = pack2(s0 * inv, s1 * inv);
            if (id < 2 * NM) AGGM[(size_t)id * 64 + lane] = pv;
            else             AGGH[(size_t)(id - 2 * NM) * 64 + lane] = pv;
        }
    }
}

// ===== streaming GEMM + L2-norm + edge-type combine + residual + LayerNorm =====
template<int NT>
__global__ __launch_bounds__(256) void gemmln_kernel(
    const u32* __restrict__ AG1, const u32* __restrict__ AG2,
    const u16* __restrict__ Tdst,
    const u16* __restrict__ WFl1, const u16* __restrict__ WFr1, const float* __restrict__ bl1,
    const u16* __restrict__ WFl2, const u16* __restrict__ WFr2, const float* __restrict__ bl2,
    const float* __restrict__ g, const float* __restrict__ be,
    float* __restrict__ outp, int N, float scale)
{
    __shared__ float redN[NT][4][16];
    __shared__ float redS[2][4][16];

    int tid = threadIdx.x;
    int wave = tid >> 6, lane = tid & 63;
    int ln16 = lane & 15, quad = lane >> 4;

    const u32* AG[2] = {AG1, AG2};
    const u16* WFl[2] = {WFl1, WFl2};
    const u16* WFr[2] = {WFr1, WFr2};
    const float* bls[2] = {bl1, bl2};

    bf16x8 BL[NT][2][4], BR[NT][2][4];
    float bv[NT][2];
    #pragma unroll
    for (int et = 0; et < NT; ++et){
        #pragma unroll
        for (int t = 0; t < 2; ++t){
            bv[et][t] = bls[et][wave * 32 + t * 16 + ln16];
            #pragma unroll
            for (int q = 0; q < 4; ++q){
                int fo = ((((wave * 2 + t) * 4 + q) * 4 + quad) * 16 + ln16) * 8;
                BL[et][t][q] = *(const bf16x8*)(WFl[et] + fo);
                BR[et][t][q] = *(const bf16x8*)(WFr[et] + fo);
            }
        }
    }
    float gv[2], bev[2];
    #pragma unroll
    for (int t = 0; t < 2; ++t){
        int col = wave * 32 + t * 16 + ln16;
        gv[t] = g[col]; bev[t] = be[col];
    }

    int tiles = (N + 15) >> 4;
    for (int tile = blockIdx.x; tile < tiles; tile += gridDim.x){
        int row0 = tile * 16;
        int ar = row0 + ln16; if (ar > N - 1) ar = N - 1;
        const u16* Ar2 = Tdst + (size_t)ar * 128 + quad * 8;

        f32x4 acc[NT][2];
        #pragma unroll
        for (int et = 0; et < NT; ++et)
            #pragma unroll
            for (int t = 0; t < 2; ++t)
                acc[et][t] = (f32x4){bv[et][t], bv[et][t], bv[et][t], bv[et][t]};

        #pragma unroll
        for (int q = 0; q < 4; ++q){
            bf16x8 afr = *(const bf16x8*)(Ar2 + q * 32);
            #pragma unroll
            for (int et = 0; et < NT; ++et){
                bf16x8 afl = *(const bf16x8*)(AG[et] + (size_t)ar * 64 + q * 16 + quad * 4);
                #pragma unroll
                for (int t = 0; t < 2; ++t){
                    acc[et][t] = __builtin_amdgcn_mfma_f32_16x16x32_bf16(afl, BL[et][t][q], acc[et][t], 0, 0, 0);
                    acc[et][t] = __builtin_amdgcn_mfma_f32_16x16x32_bf16(afr, BR[et][t][q], acc[et][t], 0, 0, 0);
                }
            }
        }

        #pragma unroll
        for (int et = 0; et < NT; ++et){
            #pragma unroll
            for (int r = 0; r < 4; ++r){
                float s = acc[et][0][r] * acc[et][0][r] + acc[et][1][r] * acc[et][1][r];
                #pragma unroll
                for (int m = 1; m < 16; m <<= 1) s += __shfl_xor(s, m);
                if (ln16 == 0) redN[et][wave][quad * 4 + r] = s;
            }
        }
        __syncthreads();

        float yv[2][4];
        float lsum[4], lsq[4];
        #pragma unroll
        for (int r = 0; r < 4; ++r){
            int r16 = quad * 4 + r;
            int row = row0 + r16;
            int crow = row < N ? row : N - 1;
            float sc[NT];
            #pragma unroll
            for (int et = 0; et < NT; ++et){
                float tot = redN[et][0][r16] + redN[et][1][r16] + redN[et][2][r16] + redN[et][3][r16];
                sc[et] = scale / fmaxf(sqrtf(tot), 1e-12f);
            }
            float s1v = 0.f, s2v = 0.f;
            #pragma unroll
            for (int t = 0; t < 2; ++t){
                int col = wave * 32 + t * 16 + ln16;
                float y = bf2f(Tdst[(size_t)crow * 128 + col]);
                #pragma unroll
                for (int et = 0; et < NT; ++et) y += acc[et][t][r] * sc[et];
                yv[t][r] = y;
                s1v += y; s2v += y * y;
            }
            #pragma unroll
            for (int m = 1; m < 16; m <<= 1){ s1v += __shfl_xor(s1v, m); s2v += __shfl_xor(s2v, m); }
            lsum[r] = s1v; lsq[r] = s2v;
        }
        if (ln16 == 0){
            #pragma unroll
            for (int r = 0; r < 4; ++r){
                redS[0][wave][quad * 4 + r] = lsum[r];
                redS[1][wave][quad * 4 + r] = lsq[r];
            }
        }
        __syncthreads();

        #pragma unroll
        for (int r = 0; r < 4; ++r){
            int r16 = quad * 4 + r;
            int row = row0 + r16;
            if (row >= N) continue;
            float S1 = redS[0][0][r16] + redS[0][1][r16] + redS[0][2][r16] + redS[0][3][r16];
            float S2 = redS[1][0][r16] + redS[1][1][r16] + redS[1][2][r16] + redS[1][3][r16];
            float mean = S1 * (1.0f / 128.0f);
            float var = S2 * (1.0f / 128.0f) - mean * mean;
            float rstd = rsqrtf(var + 1e-5f);
            #pragma unroll
            for (int t = 0; t < 2; ++t){
                int col = wave * 32 + t * 16 + ln16;
                outp[(size_t)row * 128 + col] = (yv[t][r] - mean) * rstd * gv[t] + bev[t];
            }
        }
        __syncthreads();
    }
}

extern "C" void kernel_launch(void* const* d_in, const int* in_sizes, int n_in,
                              void* d_out, int out_size, void* d_ws, size_t ws_size,
                              hipStream_t stream) {
    const float* xm    = (const float*)d_in[0];
    const float* xh    = (const float*)d_in[1];
    const float* Wnt_m = (const float*)d_in[2];  const float* bnt_m = (const float*)d_in[3];
    const float* Wnt_h = (const float*)d_in[4];  const float* bnt_h = (const float*)d_in[5];
    const float* Wl_mm = (const float*)d_in[6];  const float* bl_mm = (const float*)d_in[7];
    const float* Wr_mm = (const float*)d_in[8];
    const float* Wl_mh = (const float*)d_in[9];  const float* bl_mh = (const float*)d_in[10];
    const float* Wr_mh = (const float*)d_in[11];
    const float* Wl_hm = (const float*)d_in[12]; const float* bl_hm = (const float*)d_in[13];
    const float* Wr_hm = (const float*)d_in[14];
    const float* g_m   = (const float*)d_in[15]; const float* be_m  = (const float*)d_in[16];
    const float* g_h   = (const float*)d_in[17]; const float* be_h  = (const float*)d_in[18];
    const int* ei_mm = (const int*)d_in[19];
    const int* ei_mh = (const int*)d_in[20];
    const int* ei_hm = (const int*)d_in[21];

    const int D = 128;
    const int NM = in_sizes[0] / D;
    const int NH = in_sizes[1] / D;
    const int E1 = in_sizes[19] / 2;   // mm
    const int E2 = in_sizes[20] / 2;   // mh
    const int E3 = in_sizes[21] / 2;   // hm
    const int Esum = E1 + E2 + E3;
    const int n3 = 2 * NM + NH;        // type0: mm->M, type1: hm->M, type2: mh->H

    // chunk/range decomposition for the LDS counting sort
    const int c0 = (E1 + CHUNK - 1) / CHUNK;
    const int c1 = (E3 + CHUNK - 1) / CHUNK;
    const int c2 = (E2 + CHUNK - 1) / CHUNK;
    const int R0 = (NM + LDSN - 1) / LDSN;
    const int R1 = (NM + LDSN - 1) / LDSN;
    const int R2 = (NH + LDSN - 1) / LDSN;
    const int HB2 = c0 * R0 + c1 * R1 + c2 * R2;

    char* ws = (char*)d_ws;
    size_t woff = 0;
    auto alloc = [&](size_t bytes) -> void* {
        void* p = ws + woff;
        woff += (bytes + 255) & ~(size_t)255;
        return p;
    };
    u16* T_M   = (u16*)alloc((size_t)NM * D * 2);
    u16* T_H   = (u16*)alloc((size_t)NH * D * 2);
    u16* CNT16 = (u16*)alloc(((size_t)(c0 + c1) * NM + (size_t)c2 * NH) * 2);
    int* OFF3  = (int*)alloc((size_t)(n3 + 1) * 4);
    int* SLOT3 = (int*)alloc((size_t)Esum * 4);
    int* PART  = (int*)alloc(1024 * 4);
    u16* WF    = (u16*)alloc((size_t)6 * 16384 * 2);   // pre-swizzled bf16 weights
    u32* AGGM  = (u32*)alloc((size_t)2 * NM * 64 * 4); // mean-agg rows for M-dst (mm,hm)
    if (woff > ws_size) return;

    u16* C0p = CNT16;
    u16* C1p = C0p + (size_t)c0 * NM;
    u16* C2p = C1p + (size_t)c1 * NM;

    // d_out staging: BASE tables + RANK (dead after fill3), then AGGH (dead after
    // gemmln<1>), then final outputs.
    int* B0p = (int*)d_out;
    int* B1p = B0p + (size_t)c0 * NM;
    int* B2p = B1p + (size_t)c1 * NM;
    u16* RK  = (u16*)(B2p + (size_t)c2 * NH);
    u16* rk0 = RK, *rk1 = RK + E1, *rk2 = RK + E1 + E3;
    u32* AGGH = (u32*)d_out;

    float* OUT_M = (float*)d_out;
    float* OUT_H = (float*)d_out + (size_t)NM * D;

    const int gm = 1024, gh = 1024;
    const int scanBlocks = (n3 + 2047) / 2048;
    int Emax = E1 > E2 ? E1 : E2; if (E3 > Emax) Emax = E3;
    const dim3 egrid((Emax + 1023) / 1024, 3);

    fusedA_kernel<<<HB2 + 6 + gm + gh, 256, 0, stream>>>(
        ei_mm + E1, ei_hm + E3, ei_mh + E2,
        rk0, rk1, rk2,
        E1, E3, E2, NM, NM, NH,
        c0, c1, c2, R0, R1, R2,
        C0p, C1p, C2p, HB2,
        Wl_mm, Wr_mm, Wl_hm, Wr_hm, Wl_mh, Wr_mh, WF,
        xm, Wnt_m, bnt_m, T_M, NM,
        xh, Wnt_h, bnt_h, T_H, NH, gm, gh);

    scan_blocks_kernel<<<scanBlocks, 256, 0, stream>>>(
        C0p, C1p, C2p, c0, c1, c2, NM, NH, n3, OFF3, PART);
    colbase_kernel<<<(n3 + 255) / 256, 256, 0, stream>>>(
        C0p, C1p, C2p, B0p, B1p, B2p, c0, c1, c2, NM, NH, n3, OFF3, PART);

    fill3_kernel<<<egrid, 256, 0, stream>>>(
        ei_mm, ei_hm, ei_mh,
        ei_mm + E1, ei_hm + E3, ei_mh + E2,
        rk0, rk1, rk2,
        E1, E3, E2, NM, NM, NH,
        B0p, B1p, B2p, SLOT3);

    gather3_kernel<<<4096, 256, 0, stream>>>(
        T_M, T_H, OFF3, SLOT3, AGGM, AGGH, NM, NH);

    // H first (AGGH lives in d_out where OUT_M will go)
    gemmln_kernel<1><<<1024, 256, 0, stream>>>(
        AGGH, nullptr, T_H,
        WF + 4 * 16384, WF + 5 * 16384, bl_mh,
        nullptr, nullptr, nullptr,
        g_h, be_h, OUT_H, NH, 1.0f);
    gemmln_kernel<2><<<1024, 256, 0, stream>>>(
        AGGM, AGGM + (size_t)NM * 64, T_M,
        WF + 0 * 16384, WF + 1 * 16384, bl_mm,
        WF + 2 * 16384, WF + 3 * 16384, bl_hm,
        g_m, be_m, OUT_M, NM, 0.5f);
}

// Round 9
// 441.835 us; speedup vs baseline: 1.0879x; 1.0879x over previous
//
#include <hip/hip_runtime.h>

typedef unsigned short u16;
typedef unsigned int u32;
typedef __attribute__((ext_vector_type(8))) short bf16x8;
typedef __attribute__((ext_vector_type(4))) float f32x4;

#define LDSN 25000      // nodes per LDS range (50 KB of packed u16 counters)
#define CHUNK 32768     // edges per chunk (2^15): chunk id is a shift; rank < 2^15 fits u16

__device__ __forceinline__ float bf_lo(u32 u){ return __uint_as_float(u << 16); }
__device__ __forceinline__ float bf_hi(u32 u){ return __uint_as_float(u & 0xffff0000u); }
__device__ __forceinline__ float bf2f(u16 v){ return __uint_as_float((u32)v << 16); }
__device__ __forceinline__ u16 f2bf(float f){
    u32 u = __float_as_uint(f);
    u32 r = (u + 0x7fffu + ((u >> 16) & 1u)) >> 16;
    return (u16)r;
}
__device__ __forceinline__ u32 pack2(float a, float b){
    return (u32)f2bf(a) | ((u32)f2bf(b) << 16);
}

// ======== prep: weight-fragment pre-swizzle || ntgemm_M || ntgemm_H (NO LDS) ========
__global__ __launch_bounds__(256) void prep_kernel(
    const float* __restrict__ Wf0, const float* __restrict__ Wf1,
    const float* __restrict__ Wf2, const float* __restrict__ Wf3,
    const float* __restrict__ Wf4, const float* __restrict__ Wf5,
    u16* __restrict__ WF,
    const float* __restrict__ Xm, const float* __restrict__ Wm,
    const float* __restrict__ bm, u16* __restrict__ Tm, int NM,
    const float* __restrict__ Xh, const float* __restrict__ Wh,
    const float* __restrict__ bh, u16* __restrict__ Th, int NH,
    int gm, int gh)
{
    int bid = blockIdx.x;
    if (bid < 6){
        const float* W = bid == 0 ? Wf0 : bid == 1 ? Wf1 : bid == 2 ? Wf2 :
                         bid == 3 ? Wf3 : bid == 4 ? Wf4 : Wf5;
        u16* dst = WF + (size_t)bid * 16384;
        #pragma unroll 4
        for (int k = 0; k < 64; ++k){
            int i = k * 256 + threadIdx.x;
            int j   = i & 7;
            int l16 = (i >> 3) & 15;
            int qd  = (i >> 7) & 3;
            int q   = (i >> 9) & 3;
            int tt  = (i >> 11) & 1;
            int w   = (i >> 12) & 3;
            dst[i] = f2bf(W[(q * 32 + qd * 8 + j) * 128 + (w * 32 + tt * 16 + l16)]);
        }
        return;
    }
    bid -= 6;
    const float *A, *W, *bias; u16* C; int N, lgrid, lbid;
    if (bid < gm){ A = Xm; W = Wm; bias = bm; C = Tm; N = NM; lgrid = gm; lbid = bid; }
    else         { A = Xh; W = Wh; bias = bh; C = Th; N = NH; lgrid = gh; lbid = bid - gm; }

    int tid = threadIdx.x;
    int wave = tid >> 6, lane = tid & 63;
    int colHalf = wave & 1;
    int ln16 = lane & 15, quad = lane >> 4;

    bf16x8 Bfrag[4][4];
    #pragma unroll
    for (int t = 0; t < 4; ++t){
        int col = colHalf * 64 + t * 16 + ln16;
        #pragma unroll
        for (int q = 0; q < 4; ++q){
            bf16x8 f;
            #pragma unroll
            for (int j = 0; j < 8; ++j)
                f[j] = (short)f2bf(W[(q * 32 + quad * 8 + j) * 128 + col]);
            Bfrag[t][q] = f;
        }
    }
    float bv[4];
    #pragma unroll
    for (int t = 0; t < 4; ++t)
        bv[t] = bias[colHalf * 64 + t * 16 + ln16];

    int rowBlocks = (N + 15) >> 4;
    for (int rb = lbid * 2 + (wave >> 1); rb < rowBlocks; rb += lgrid * 2){
        int row0 = rb * 16;
        int ar = row0 + ln16; if (ar > N - 1) ar = N - 1;
        const float* Arow = A + (size_t)ar * 128 + quad * 8;
        bf16x8 Af[4];
        #pragma unroll
        for (int q = 0; q < 4; ++q){
            f32x4 lo = *(const f32x4*)(Arow + q * 32);
            f32x4 hi = *(const f32x4*)(Arow + q * 32 + 4);
            bf16x8 f;
            #pragma unroll
            for (int j = 0; j < 4; ++j){ f[j] = (short)f2bf(lo[j]); f[4+j] = (short)f2bf(hi[j]); }
            Af[q] = f;
        }
        f32x4 acc[4];
        #pragma unroll
        for (int t = 0; t < 4; ++t) acc[t] = (f32x4){bv[t], bv[t], bv[t], bv[t]};
        #pragma unroll
        for (int q = 0; q < 4; ++q)
            #pragma unroll
            for (int t = 0; t < 4; ++t)
                acc[t] = __builtin_amdgcn_mfma_f32_16x16x32_bf16(Af[q], Bfrag[t][q], acc[t], 0, 0, 0);
        #pragma unroll
        for (int t = 0; t < 4; ++t){
            int col = colHalf * 64 + t * 16 + ln16;
            #pragma unroll
            for (int r = 0; r < 4; ++r){
                int row = row0 + quad * 4 + r;
                if (row < N) C[(size_t)row * 128 + col] = f2bf(acc[t][r]);
            }
        }
    }
}

// ======== histL: packed-LDS histogram + per-edge rank; many small blocks, no tail ========
__global__ __launch_bounds__(256) void histL_kernel(
    const int* __restrict__ d0, const int* __restrict__ d1, const int* __restrict__ d2,
    u16* __restrict__ rk0, u16* __restrict__ rk1, u16* __restrict__ rk2,
    int E0, int E1, int E2, int n0, int n1, int n2,
    int c0, int c1, int c2, int R0, int R1, int R2,
    u16* __restrict__ C0, u16* __restrict__ C1, u16* __restrict__ C2)
{
    __shared__ u32 lc[LDSN / 2];
    int bid = blockIdx.x;
    const int* dp; u16 *rk, *cp; int E, n, cc, rr;
    if (bid < c0 * R0){ dp = d0; rk = rk0; cp = C0; E = E0; n = n0; cc = bid / R0; rr = bid % R0; }
    else if (bid < c0 * R0 + c1 * R1){ int l = bid - c0 * R0; dp = d1; rk = rk1; cp = C1; E = E1; n = n1; cc = l / R1; rr = l % R1; }
    else { int l = bid - c0 * R0 - c1 * R1; dp = d2; rk = rk2; cp = C2; E = E2; n = n2; cc = l / R2; rr = l % R2; }
    for (int i = threadIdx.x; i < LDSN / 2; i += 256) lc[i] = 0;
    __syncthreads();
    int r0 = rr * LDSN, r1 = min(r0 + LDSN, n);
    int i0 = cc * CHUNK, i1 = min(i0 + CHUNK, E);
    int i = i0 + threadIdx.x;
    for (; i + 768 < i1; i += 1024){
        int xa = dp[i], xb = dp[i + 256], xc = dp[i + 512], xd = dp[i + 768];
        if ((unsigned)xa < (unsigned)n && xa >= r0 && xa < r1){
            int lx = xa - r0; int sh = (lx & 1) << 4;
            u32 old = atomicAdd(&lc[lx >> 1], 1u << sh);
            rk[i] = (u16)((old >> sh) & 0xffffu);
        }
        if ((unsigned)xb < (unsigned)n && xb >= r0 && xb < r1){
            int lx = xb - r0; int sh = (lx & 1) << 4;
            u32 old = atomicAdd(&lc[lx >> 1], 1u << sh);
            rk[i + 256] = (u16)((old >> sh) & 0xffffu);
        }
        if ((unsigned)xc < (unsigned)n && xc >= r0 && xc < r1){
            int lx = xc - r0; int sh = (lx & 1) << 4;
            u32 old = atomicAdd(&lc[lx >> 1], 1u << sh);
            rk[i + 512] = (u16)((old >> sh) & 0xffffu);
        }
        if ((unsigned)xd < (unsigned)n && xd >= r0 && xd < r1){
            int lx = xd - r0; int sh = (lx & 1) << 4;
            u32 old = atomicAdd(&lc[lx >> 1], 1u << sh);
            rk[i + 768] = (u16)((old >> sh) & 0xffffu);
        }
    }
    for (; i < i1; i += 256){
        int x = dp[i];
        if ((unsigned)x < (unsigned)n && x >= r0 && x < r1){
            int lx = x - r0;
            int sh = (lx & 1) << 4;
            u32 old = atomicAdd(&lc[lx >> 1], 1u << sh);
            rk[i] = (u16)((old >> sh) & 0xffffu);
        }
    }
    __syncthreads();
    u16* op = cp + (size_t)cc * n;
    for (int x = r0 + threadIdx.x; x < r1; x += 256){
        int lx = x - r0;
        op[x] = (u16)((lc[lx >> 1] >> ((lx & 1) << 4)) & 0xffffu);
    }
}

// ---------------- scan: totals from per-chunk u16 counts (intra-block prefix + partials) ----------------
__global__ __launch_bounds__(256) void scan_blocks_kernel(
    const u16* __restrict__ C0, const u16* __restrict__ C1, const u16* __restrict__ C2,
    int c0, int c1, int c2, int NM, int NH, int n,
    int* __restrict__ off, int* __restrict__ part)
{
    __shared__ int lds[256];
    int tid = threadIdx.x;
    int base = blockIdx.x * 2048 + tid * 8;
    int v[8]; int s = 0;
    #pragma unroll
    for (int j = 0; j < 8; ++j){
        int idx = base + j;
        int tot = 0;
        if (idx < n){
            const u16* cp; int ch, w, x;
            if (idx < NM){ cp = C0; ch = c0; w = NM; x = idx; }
            else if (idx < 2 * NM){ cp = C1; ch = c1; w = NM; x = idx - NM; }
            else { cp = C2; ch = c2; w = NH; x = idx - 2 * NM; }
            for (int cc = 0; cc < ch; ++cc) tot += cp[(size_t)cc * w + x];
        }
        v[j] = s; s += tot;
    }
    lds[tid] = s;
    __syncthreads();
    for (int d = 1; d < 256; d <<= 1){
        int t = (tid >= d) ? lds[tid - d] : 0;
        __syncthreads();
        lds[tid] += t;
        __syncthreads();
    }
    int thrBase = (tid > 0) ? lds[tid - 1] : 0;
    if (tid == 255) part[blockIdx.x] = lds[255];
    #pragma unroll
    for (int j = 0; j < 8; ++j){
        int idx = base + j;
        if (idx < n) off[idx] = thrBase + v[j];
    }
}

// ---------------- colbase: in-thread part prefix; off += prefix; BASE_t[c][x]; off[n] ----------------
__global__ __launch_bounds__(256) void colbase_kernel(
    const u16* __restrict__ C0, const u16* __restrict__ C1, const u16* __restrict__ C2,
    int* __restrict__ B0, int* __restrict__ B1, int* __restrict__ B2,
    int c0, int c1, int c2, int NM, int NH, int n,
    int* __restrict__ off, const int* __restrict__ part)
{
    int idx = blockIdx.x * 256 + threadIdx.x;
    if (idx >= n) return;
    int pb = idx >> 11;
    int p = 0;
    for (int k = 0; k < pb; ++k) p += part[k];
    int run = off[idx] + p;
    off[idx] = run;
    const u16* cp; int* bp; int ch, w, x;
    if (idx < NM){ cp = C0; bp = B0; ch = c0; w = NM; x = idx; }
    else if (idx < 2 * NM){ cp = C1; bp = B1; ch = c1; w = NM; x = idx - NM; }
    else { cp = C2; bp = B2; ch = c2; w = NH; x = idx - 2 * NM; }
    for (int cc = 0; cc < ch; ++cc){
        bp[(size_t)cc * w + x] = run;
        run += cp[(size_t)cc * w + x];
    }
    if (idx == n - 1) off[n] = run;
}

// ===== fill: atomic-free, LDS-free scatter: slot = BASE[chunk][dst] + rank =====
__global__ __launch_bounds__(256) void fill3_kernel(
    const int* __restrict__ s0, const int* __restrict__ s1, const int* __restrict__ s2,
    const int* __restrict__ d0, const int* __restrict__ d1, const int* __restrict__ d2,
    const u16* __restrict__ rk0, const u16* __restrict__ rk1, const u16* __restrict__ rk2,
    int E0, int E1, int E2, int n0, int n1, int n2,
    const int* __restrict__ B0, const int* __restrict__ B1, const int* __restrict__ B2,
    int* __restrict__ slot)
{
    int t = blockIdx.y;
    const int* sp = t == 0 ? s0 : (t == 1 ? s1 : s2);
    const int* dp = t == 0 ? d0 : (t == 1 ? d1 : d2);
    const u16* rk = t == 0 ? rk0 : (t == 1 ? rk1 : rk2);
    const int* bp = t == 0 ? B0 : (t == 1 ? B1 : B2);
    int E = t == 0 ? E0 : (t == 1 ? E1 : E2);
    int n = t == 0 ? n0 : (t == 1 ? n1 : n2);
    int base = blockIdx.x * 1024 + threadIdx.x;
    #pragma unroll
    for (int k = 0; k < 4; ++k){
        int i = base + k * 256;
        if (i < E){
            int x = dp[i];
            if ((unsigned)x < (unsigned)n){
                int cc = i / CHUNK;
                slot[bp[(size_t)cc * n + x] + (int)rk[i]] = sp[i];
            }
        }
    }
}

// ===== gather: 4 rows per wave (prefetched off/slot) — at random-fetch ceiling, unchanged =====
__global__ __launch_bounds__(256) void gather3_kernel(
    const u16* __restrict__ TM, const u16* __restrict__ TH,
    const int* __restrict__ off, const int* __restrict__ slot,
    u32* __restrict__ AGGM, u32* __restrict__ AGGH, int NM, int NH)
{
    int n3 = 2 * NM + NH;
    int wid = (int)((blockIdx.x * 256u + threadIdx.x) >> 6);
    int lane = threadIdx.x & 63;
    int nw = (gridDim.x * 256) >> 6;

    for (int id0 = wid * 4; id0 < n3; id0 += nw * 4){
        int bb[4], dg[4], tk[4], ms[4], ns[4];
        const u16* Ts[4];
        #pragma unroll
        for (int r = 0; r < 4; ++r){
            int id = id0 + r;
            int b = 0, e = 0;
            if (id < n3){ b = off[id]; e = off[id + 1]; }
            bb[r] = b;
            int deg = e - b; dg[r] = deg;
            int take = deg < 64 ? deg : 64; tk[r] = take;
            const u16* Tsrc; int nsrc;
            if (id < NM){ Tsrc = TM; nsrc = NM; }
            else if (id < 2 * NM){ Tsrc = TH; nsrc = NH; }
            else { Tsrc = TM; nsrc = NM; }
            Ts[r] = Tsrc; ns[r] = nsrc;
            int s = 0;
            if (lane < take){
                s = slot[b + lane];
                if ((unsigned)s >= (unsigned)nsrc) s = 0;
            }
            ms[r] = s;
        }

        #pragma unroll
        for (int r = 0; r < 4; ++r){
            int id = id0 + r;
            if (id >= n3) break;
            const u16* Tsrc = Ts[r];
            int take = tk[r];
            float a0=0.f,a1=0.f,b0f=0.f,b1f=0.f,c0=0.f,c1=0.f,d0f=0.f,d1f=0.f;
            float e0=0.f,e1=0.f,f0=0.f,f1=0.f,g0=0.f,g1=0.f,h0=0.f,h1=0.f;
            int j = 0;
            for (; j + 8 <= take; j += 8){
                int i0 = __shfl(ms[r], j);     int i1 = __shfl(ms[r], j + 1);
                int i2 = __shfl(ms[r], j + 2); int i3 = __shfl(ms[r], j + 3);
                int i4 = __shfl(ms[r], j + 4); int i5 = __shfl(ms[r], j + 5);
                int i6 = __shfl(ms[r], j + 6); int i7 = __shfl(ms[r], j + 7);
                u32 u0 = *(const u32*)(Tsrc + (size_t)i0 * 128 + lane * 2);
                u32 u1 = *(const u32*)(Tsrc + (size_t)i1 * 128 + lane * 2);
                u32 u2 = *(const u32*)(Tsrc + (size_t)i2 * 128 + lane * 2);
                u32 u3 = *(const u32*)(Tsrc + (size_t)i3 * 128 + lane * 2);
                u32 u4 = *(const u32*)(Tsrc + (size_t)i4 * 128 + lane * 2);
                u32 u5 = *(const u32*)(Tsrc + (size_t)i5 * 128 + lane * 2);
                u32 u6 = *(const u32*)(Tsrc + (size_t)i6 * 128 + lane * 2);
                u32 u7 = *(const u32*)(Tsrc + (size_t)i7 * 128 + lane * 2);
                a0 += bf_lo(u0); a1 += bf_hi(u0);
                b0f += bf_lo(u1); b1f += bf_hi(u1);
                c0 += bf_lo(u2); c1 += bf_hi(u2);
                d0f += bf_lo(u3); d1f += bf_hi(u3);
                e0 += bf_lo(u4); e1 += bf_hi(u4);
                f0 += bf_lo(u5); f1 += bf_hi(u5);
                g0 += bf_lo(u6); g1 += bf_hi(u6);
                h0 += bf_lo(u7); h1 += bf_hi(u7);
            }
            for (; j + 4 <= take; j += 4){
                int i0 = __shfl(ms[r], j);     int i1 = __shfl(ms[r], j + 1);
                int i2 = __shfl(ms[r], j + 2); int i3 = __shfl(ms[r], j + 3);
                u32 u0 = *(const u32*)(Tsrc + (size_t)i0 * 128 + lane * 2);
                u32 u1 = *(const u32*)(Tsrc + (size_t)i1 * 128 + lane * 2);
                u32 u2 = *(const u32*)(Tsrc + (size_t)i2 * 128 + lane * 2);
                u32 u3 = *(const u32*)(Tsrc + (size_t)i3 * 128 + lane * 2);
                a0 += bf_lo(u0); a1 += bf_hi(u0);
                b0f += bf_lo(u1); b1f += bf_hi(u1);
                c0 += bf_lo(u2); c1 += bf_hi(u2);
                d0f += bf_lo(u3); d1f += bf_hi(u3);
            }
            for (; j < take; ++j){
                int i0 = __shfl(ms[r], j);
                u32 u0 = *(const u32*)(Tsrc + (size_t)i0 * 128 + lane * 2);
                a0 += bf_lo(u0); a1 += bf_hi(u0);
            }
            for (int j2 = bb[r] + 64; j2 < bb[r] + dg[r]; ++j2){
                int i0 = slot[j2];
                if ((unsigned)i0 >= (unsigned)ns[r]) i0 = 0;
                u32 u0 = *(const u32*)(Tsrc + (size_t)i0 * 128 + lane * 2);
                a0 += bf_lo(u0); a1 += bf_hi(u0);
            }
            float s0 = ((a0 + b0f) + (c0 + d0f)) + ((e0 + f0) + (g0 + h0));
            float s1 = ((a1 + b1f) + (c1 + d1f)) + ((e1 + f1) + (g1 + h1));
            float inv = 1.0f / (float)(dg[r] < 1 ? 1 : dg[r]);
            u32 pv = pack2(s0 * inv, s1 * inv);
            if (id < 2 * NM) AGGM[(size_t)id * 64 + lane] = pv;
            else             AGGH[(size_t)(id - 2 * NM) * 64 + lane] = pv;
        }
    }
}

// ===== streaming GEMM + L2-norm + edge-type combine + residual + LayerNorm =====
template<int NT>
__global__ __launch_bounds__(256) void gemmln_kernel(
    const u32* __restrict__ AG1, const u32* __restrict__ AG2,
    const u16* __restrict__ Tdst,
    const u16* __restrict__ WFl1, const u16* __restrict__ WFr1, const float* __restrict__ bl1,
    const u16* __restrict__ WFl2, const u16* __restrict__ WFr2, const float* __restrict__ bl2,
    const float* __restrict__ g, const float* __restrict__ be,
    float* __restrict__ outp, int N, float scale)
{
    __shared__ float redN[NT][4][16];
    __shared__ float redS[2][4][16];

    int tid = threadIdx.x;
    int wave = tid >> 6, lane = tid & 63;
    int ln16 = lane & 15, quad = lane >> 4;

    const u32* AG[2] = {AG1, AG2};
    const u16* WFl[2] = {WFl1, WFl2};
    const u16* WFr[2] = {WFr1, WFr2};
    const float* bls[2] = {bl1, bl2};

    bf16x8 BL[NT][2][4], BR[NT][2][4];
    float bv[NT][2];
    #pragma unroll
    for (int et = 0; et < NT; ++et){
        #pragma unroll
        for (int t = 0; t < 2; ++t){
            bv[et][t] = bls[et][wave * 32 + t * 16 + ln16];
            #pragma unroll
            for (int q = 0; q < 4; ++q){
                int fo = ((((wave * 2 + t) * 4 + q) * 4 + quad) * 16 + ln16) * 8;
                BL[et][t][q] = *(const bf16x8*)(WFl[et] + fo);
                BR[et][t][q] = *(const bf16x8*)(WFr[et] + fo);
            }
        }
    }
    float gv[2], bev[2];
    #pragma unroll
    for (int t = 0; t < 2; ++t){
        int col = wave * 32 + t * 16 + ln16;
        gv[t] = g[col]; bev[t] = be[col];
    }

    int tiles = (N + 15) >> 4;
    for (int tile = blockIdx.x; tile < tiles; tile += gridDim.x){
        int row0 = tile * 16;
        int ar = row0 + ln16; if (ar > N - 1) ar = N - 1;
        const u16* Ar2 = Tdst + (size_t)ar * 128 + quad * 8;

        f32x4 acc[NT][2];
        #pragma unroll
        for (int et = 0; et < NT; ++et)
            #pragma unroll
            for (int t = 0; t < 2; ++t)
                acc[et][t] = (f32x4){bv[et][t], bv[et][t], bv[et][t], bv[et][t]};

        #pragma unroll
        for (int q = 0; q < 4; ++q){
            bf16x8 afr = *(const bf16x8*)(Ar2 + q * 32);
            #pragma unroll
            for (int et = 0; et < NT; ++et){
                bf16x8 afl = *(const bf16x8*)(AG[et] + (size_t)ar * 64 + q * 16 + quad * 4);
                #pragma unroll
                for (int t = 0; t < 2; ++t){
                    acc[et][t] = __builtin_amdgcn_mfma_f32_16x16x32_bf16(afl, BL[et][t][q], acc[et][t], 0, 0, 0);
                    acc[et][t] = __builtin_amdgcn_mfma_f32_16x16x32_bf16(afr, BR[et][t][q], acc[et][t], 0, 0, 0);
                }
            }
        }

        #pragma unroll
        for (int et = 0; et < NT; ++et){
            #pragma unroll
            for (int r = 0; r < 4; ++r){
                float s = acc[et][0][r] * acc[et][0][r] + acc[et][1][r] * acc[et][1][r];
                #pragma unroll
                for (int m = 1; m < 16; m <<= 1) s += __shfl_xor(s, m);
                if (ln16 == 0) redN[et][wave][quad * 4 + r] = s;
            }
        }
        __syncthreads();

        float yv[2][4];
        float lsum[4], lsq[4];
        #pragma unroll
        for (int r = 0; r < 4; ++r){
            int r16 = quad * 4 + r;
            int row = row0 + r16;
            int crow = row < N ? row : N - 1;
            float sc[NT];
            #pragma unroll
            for (int et = 0; et < NT; ++et){
                float tot = redN[et][0][r16] + redN[et][1][r16] + redN[et][2][r16] + redN[et][3][r16];
                sc[et] = scale / fmaxf(sqrtf(tot), 1e-12f);
            }
            float s1v = 0.f, s2v = 0.f;
            #pragma unroll
            for (int t = 0; t < 2; ++t){
                int col = wave * 32 + t * 16 + ln16;
                float y = bf2f(Tdst[(size_t)crow * 128 + col]);
                #pragma unroll
                for (int et = 0; et < NT; ++et) y += acc[et][t][r] * sc[et];
                yv[t][r] = y;
                s1v += y; s2v += y * y;
            }
            #pragma unroll
            for (int m = 1; m < 16; m <<= 1){ s1v += __shfl_xor(s1v, m); s2v += __shfl_xor(s2v, m); }
            lsum[r] = s1v; lsq[r] = s2v;
        }
        if (ln16 == 0){
            #pragma unroll
            for (int r = 0; r < 4; ++r){
                redS[0][wave][quad * 4 + r] = lsum[r];
                redS[1][wave][quad * 4 + r] = lsq[r];
            }
        }
        __syncthreads();

        #pragma unroll
        for (int r = 0; r < 4; ++r){
            int r16 = quad * 4 + r;
            int row = row0 + r16;
            if (row >= N) continue;
            float S1 = redS[0][0][r16] + redS[0][1][r16] + redS[0][2][r16] + redS[0][3][r16];
            float S2 = redS[1][0][r16] + redS[1][1][r16] + redS[1][2][r16] + redS[1][3][r16];
            float mean = S1 * (1.0f / 128.0f);
            float var = S2 * (1.0f / 128.0f) - mean * mean;
            float rstd = rsqrtf(var + 1e-5f);
            #pragma unroll
            for (int t = 0; t < 2; ++t){
                int col = wave * 32 + t * 16 + ln16;
                outp[(size_t)row * 128 + col] = (yv[t][r] - mean) * rstd * gv[t] + bev[t];
            }
        }
        __syncthreads();
    }
}

extern "C" void kernel_launch(void* const* d_in, const int* in_sizes, int n_in,
                              void* d_out, int out_size, void* d_ws, size_t ws_size,
                              hipStream_t stream) {
    const float* xm    = (const float*)d_in[0];
    const float* xh    = (const float*)d_in[1];
    const float* Wnt_m = (const float*)d_in[2];  const float* bnt_m = (const float*)d_in[3];
    const float* Wnt_h = (const float*)d_in[4];  const float* bnt_h = (const float*)d_in[5];
    const float* Wl_mm = (const float*)d_in[6];  const float* bl_mm = (const float*)d_in[7];
    const float* Wr_mm = (const float*)d_in[8];
    const float* Wl_mh = (const float*)d_in[9];  const float* bl_mh = (const float*)d_in[10];
    const float* Wr_mh = (const float*)d_in[11];
    const float* Wl_hm = (const float*)d_in[12]; const float* bl_hm = (const float*)d_in[13];
    const float* Wr_hm = (const float*)d_in[14];
    const float* g_m   = (const float*)d_in[15]; const float* be_m  = (const float*)d_in[16];
    const float* g_h   = (const float*)d_in[17]; const float* be_h  = (const float*)d_in[18];
    const int* ei_mm = (const int*)d_in[19];
    const int* ei_mh = (const int*)d_in[20];
    const int* ei_hm = (const int*)d_in[21];

    const int D = 128;
    const int NM = in_sizes[0] / D;
    const int NH = in_sizes[1] / D;
    const int E1 = in_sizes[19] / 2;   // mm
    const int E2 = in_sizes[20] / 2;   // mh
    const int E3 = in_sizes[21] / 2;   // hm
    const int Esum = E1 + E2 + E3;
    const int n3 = 2 * NM + NH;        // type0: mm->M, type1: hm->M, type2: mh->H

    // chunk/range decomposition for the LDS counting sort
    const int c0 = (E1 + CHUNK - 1) / CHUNK;
    const int c1 = (E3 + CHUNK - 1) / CHUNK;
    const int c2 = (E2 + CHUNK - 1) / CHUNK;
    const int R0 = (NM + LDSN - 1) / LDSN;
    const int R1 = (NM + LDSN - 1) / LDSN;
    const int R2 = (NH + LDSN - 1) / LDSN;
    const int HB2 = c0 * R0 + c1 * R1 + c2 * R2;

    char* ws = (char*)d_ws;
    size_t woff = 0;
    auto alloc = [&](size_t bytes) -> void* {
        void* p = ws + woff;
        woff += (bytes + 255) & ~(size_t)255;
        return p;
    };
    u16* T_M   = (u16*)alloc((size_t)NM * D * 2);
    u16* T_H   = (u16*)alloc((size_t)NH * D * 2);
    u16* CNT16 = (u16*)alloc(((size_t)(c0 + c1) * NM + (size_t)c2 * NH) * 2);
    int* OFF3  = (int*)alloc((size_t)(n3 + 1) * 4);
    int* SLOT3 = (int*)alloc((size_t)Esum * 4);
    int* PART  = (int*)alloc(1024 * 4);
    u16* WF    = (u16*)alloc((size_t)6 * 16384 * 2);   // pre-swizzled bf16 weights
    u32* AGGM  = (u32*)alloc((size_t)2 * NM * 64 * 4); // mean-agg rows for M-dst (mm,hm)
    if (woff > ws_size) return;

    u16* C0p = CNT16;
    u16* C1p = C0p + (size_t)c0 * NM;
    u16* C2p = C1p + (size_t)c1 * NM;

    // d_out staging: BASE tables + RANK (dead after fill3), then AGGH (dead after
    // gemmln<1>), then final outputs.
    int* B0p = (int*)d_out;
    int* B1p = B0p + (size_t)c0 * NM;
    int* B2p = B1p + (size_t)c1 * NM;
    u16* RK  = (u16*)(B2p + (size_t)c2 * NH);
    u16* rk0 = RK, *rk1 = RK + E1, *rk2 = RK + E1 + E3;
    u32* AGGH = (u32*)d_out;

    float* OUT_M = (float*)d_out;
    float* OUT_H = (float*)d_out + (size_t)NM * D;

    const int gm = 1024, gh = 1024;
    const int scanBlocks = (n3 + 2047) / 2048;
    int Emax = E1 > E2 ? E1 : E2; if (E3 > Emax) Emax = E3;
    const dim3 egrid((Emax + 1023) / 1024, 3);

    prep_kernel<<<6 + gm + gh, 256, 0, stream>>>(
        Wl_mm, Wr_mm, Wl_hm, Wr_hm, Wl_mh, Wr_mh, WF,
        xm, Wnt_m, bnt_m, T_M, NM,
        xh, Wnt_h, bnt_h, T_H, NH, gm, gh);

    histL_kernel<<<HB2, 256, 0, stream>>>(
        ei_mm + E1, ei_hm + E3, ei_mh + E2,
        rk0, rk1, rk2,
        E1, E3, E2, NM, NM, NH,
        c0, c1, c2, R0, R1, R2,
        C0p, C1p, C2p);

    scan_blocks_kernel<<<scanBlocks, 256, 0, stream>>>(
        C0p, C1p, C2p, c0, c1, c2, NM, NH, n3, OFF3, PART);
    colbase_kernel<<<(n3 + 255) / 256, 256, 0, stream>>>(
        C0p, C1p, C2p, B0p, B1p, B2p, c0, c1, c2, NM, NH, n3, OFF3, PART);

    fill3_kernel<<<egrid, 256, 0, stream>>>(
        ei_mm, ei_hm, ei_mh,
        ei_mm + E1, ei_hm + E3, ei_mh + E2,
        rk0, rk1, rk2,
        E1, E3, E2, NM, NM, NH,
        B0p, B1p, B2p, SLOT3);

    gather3_kernel<<<4096, 256, 0, stream>>>(
        T_M, T_H, OFF3, SLOT3, AGGM, AGGH, NM, NH);

    // H first (AGGH lives in d_out where OUT_M will go)
    gemmln_kernel<1><<<1024, 256, 0, stream>>>(
        AGGH, nullptr, T_H,
        WF + 4 * 16384, WF + 5 * 16384, bl_mh,
        nullptr, nullptr, nullptr,
        g_h, be_h, OUT_H, NH, 1.0f);
    gemmln_kernel<2><<<1024, 256, 0, stream>>>(
        AGGM, AGGM + (size_t)NM * 64, T_M,
        WF + 0 * 16384, WF + 1 * 16384, bl_mm,
        WF + 2 * 16384, WF + 3 * 16384, bl_hm,
        g_m, be_m, OUT_M, NM, 0.5f);
}